// Round 3
// baseline (381.980 us; speedup 1.0000x reference)
//
#include <hip/hip_runtime.h>

// SVD predict + feature-concat kernel, 2 rows per 16-lane group.
// Each 16-lane group handles rows (g) and (g + batch/2): all four 16-B
// gathers (p0,q0,p1,q1) are issued before any dependent use to double
// memory-level parallelism. Feature writes are non-temporal (write-once
// stream). Dot products reduced via __shfl_down over the 16-lane segment.

typedef float vfloat4 __attribute__((ext_vector_type(4)));

__global__ __launch_bounds__(256) void svd_predict_kernel(
    const int* __restrict__ user_item,
    const float* __restrict__ pu,
    const float* __restrict__ qi,
    const float* __restrict__ bu,
    const float* __restrict__ bi,
    const float* __restrict__ gm_ptr,
    float* __restrict__ out,
    int batch)
{
    const float gm = gm_ptr[0];
    const int lane16 = threadIdx.x & 15;
    const int grp = (int)((blockIdx.x * blockDim.x + threadIdx.x) >> 4);
    const int half = (batch + 1) >> 1;
    if (grp >= half) return;

    const int r0 = grp;
    const int r1 = grp + half;
    const bool has1 = (r1 < batch);

    // index loads (dwordx2 each; uniform across the 16-lane group)
    const int2 ui0 = *reinterpret_cast<const int2*>(user_item + 2 * (size_t)r0);
    const int2 ui1 = has1 ? *reinterpret_cast<const int2*>(user_item + 2 * (size_t)r1)
                          : ui0;   // safe dummy address when r1 out of range

    const vfloat4* p0 = (const vfloat4*)(pu + (size_t)ui0.x * 64);
    const vfloat4* q0 = (const vfloat4*)(qi + (size_t)ui0.y * 64);
    const vfloat4* p1 = (const vfloat4*)(pu + (size_t)ui1.x * 64);
    const vfloat4* q1 = (const vfloat4*)(qi + (size_t)ui1.y * 64);

    // issue all four gathers before any dependent consume (4×16 B in flight)
    vfloat4 pv0 = p0[lane16];
    vfloat4 qv0 = q0[lane16];
    vfloat4 pv1 = p1[lane16];
    vfloat4 qv1 = q1[lane16];

    // features: out[batch + row*128 + {0..63 | 64..127}], nt write-once stream
    vfloat4* f0 = (vfloat4*)(out + (size_t)batch + (size_t)r0 * 128);
    __builtin_nontemporal_store(pv0, f0 + lane16);
    __builtin_nontemporal_store(qv0, f0 + 16 + lane16);
    if (has1) {
        vfloat4* f1 = (vfloat4*)(out + (size_t)batch + (size_t)r1 * 128);
        __builtin_nontemporal_store(pv1, f1 + lane16);
        __builtin_nontemporal_store(qv1, f1 + 16 + lane16);
    }

    float s0 = pv0.x * qv0.x + pv0.y * qv0.y + pv0.z * qv0.z + pv0.w * qv0.w;
    float s1 = pv1.x * qv1.x + pv1.y * qv1.y + pv1.z * qv1.z + pv1.w * qv1.w;
    // reduce both across the 16-lane segment
    s0 += __shfl_down(s0, 8, 16);
    s1 += __shfl_down(s1, 8, 16);
    s0 += __shfl_down(s0, 4, 16);
    s1 += __shfl_down(s1, 4, 16);
    s0 += __shfl_down(s0, 2, 16);
    s1 += __shfl_down(s1, 2, 16);
    s0 += __shfl_down(s0, 1, 16);
    s1 += __shfl_down(s1, 1, 16);

    if (lane16 == 0) {
        float pred0 = gm + bu[ui0.x] + bi[ui0.y] + s0;
        pred0 = fminf(fmaxf(pred0, 1.0f), 5.0f);
        out[r0] = pred0;
        if (has1) {
            float pred1 = gm + bu[ui1.x] + bi[ui1.y] + s1;
            pred1 = fminf(fmaxf(pred1, 1.0f), 5.0f);
            out[r1] = pred1;
        }
    }
}

extern "C" void kernel_launch(void* const* d_in, const int* in_sizes, int n_in,
                              void* d_out, int out_size, void* d_ws, size_t ws_size,
                              hipStream_t stream) {
    const int*   user_item = (const int*)d_in[0];
    const float* pu        = (const float*)d_in[1];
    const float* qi        = (const float*)d_in[2];
    const float* bu        = (const float*)d_in[3];
    const float* bi        = (const float*)d_in[4];
    const float* gm        = (const float*)d_in[5];
    float*       out       = (float*)d_out;

    const int batch = in_sizes[0] / 2;            // user_item is (BATCH, 2)
    const int half  = (batch + 1) / 2;            // 2 rows per 16-lane group
    const int rows_per_block = 256 / 16;
    const int blocks = (half + rows_per_block - 1) / rows_per_block;

    svd_predict_kernel<<<blocks, 256, 0, stream>>>(
        user_item, pu, qi, bu, bi, gm, out, batch);
}